// Round 4
// baseline (556.852 us; speedup 1.0000x reference)
//
#include <hip/hip_runtime.h>
#include <hip/hip_bf16.h>

// Problem constants (match reference)
#define NN 100000
#define EE 1000000
#define FDIM 64
#define NREL 16
#define NBASE 8
#define HN (NN * FDIM)
#define H4 (HN / 4)
#define WSZ (NREL * FDIM * FDIM)   // 65536 elements
#define NPAD 100032                // NN padded to multiple of 64
#define PCOLS 1024                 // R*OUT
#define EGX 128                    // fallback: blocks per rel in edge kernel

typedef __attribute__((ext_vector_type(8))) short short8;
typedef __attribute__((ext_vector_type(4))) float f32x4;

static __device__ __forceinline__ ushort f2bf(float f) {
    __hip_bfloat16 b = __float2bfloat16(f);
    return *(ushort*)&b;
}
static __device__ __forceinline__ float bf2f(ushort u) {
    unsigned x = ((unsigned)u) << 16;
    float f;
    __builtin_memcpy(&f, &x, 4);
    return f;
}

// ---------------- shared prep kernel (both paths) ----------------
// gid < czn      : zero the histogram counters
// gid < WSZ      : WT[c][d] = bf16 rel-weight, reinterpret-view-faithful:
//                  W[r][d][o] = sum_b w_comp[d&15,b]*weight[(4r+(d>>4))*512+b*64+o]
//                  stored transposed [c=r*64+o][d] (= GEMM B operand layout)
// gid < H4       : out = relu(h) fp32; hb = bf16(h); optionally zero h2
__global__ void prep_kernel(const float4* __restrict__ h4, float4* __restrict__ out4,
                            ushort2* __restrict__ hb2,
                            const float* __restrict__ weight,
                            const float* __restrict__ w_comp, ushort* __restrict__ WT,
                            int* __restrict__ cnt, int czn,
                            float4* __restrict__ h2z, int zero_h2) {
    int gid = blockIdx.x * blockDim.x + threadIdx.x;
    if (gid < czn) cnt[gid] = 0;
    if (gid < WSZ) {
        int r = gid >> 12;
        int o = (gid >> 6) & 63;
        int d = gid & 63;
        const float* wc = w_comp + (d & 15) * NBASE;
        const float* wv = weight + (size_t)(4 * r + (d >> 4)) * 512 + o;
        float acc = 0.f;
#pragma unroll
        for (int b = 0; b < NBASE; ++b)
            acc = fmaf(wc[b], wv[b * 64], acc);
        WT[gid] = f2bf(acc);
    }
    if (gid < H4) {
        float4 v = h4[gid];
        ushort2 lo, hi;
        lo.x = f2bf(v.x); lo.y = f2bf(v.y);
        hi.x = f2bf(v.z); hi.y = f2bf(v.w);
        hb2[2 * gid] = lo;
        hb2[2 * gid + 1] = hi;
        v.x = fmaxf(v.x, 0.f); v.y = fmaxf(v.y, 0.f);
        v.z = fmaxf(v.z, 0.f); v.w = fmaxf(v.w, 0.f);
        out4[gid] = v;
        if (zero_h2) h2z[gid] = make_float4(0.f, 0.f, 0.f, 0.f);
    }
}

// ================= MAIN PATH (proj + dst-sort, atomic-free) =================

// Dense GEMM: projb[n][c] = sum_d hb[n][d] * WT[c][d], n<NPAD, c<1024.
// Wave tile 64x64; block = 64 rows x 256 cols. Layouts HW-verified (round 3):
// A: m=lane&15,k=quad*8+j; B: n=lane&15,k=quad*8+j; D: col=lane&15,row=quad*4+reg.
// blockIdx.y==0 blocks also accumulate the dst histogram (fused to save a launch).
__global__ __launch_bounds__(256) void proj_gemm_kernel(
    const ushort* __restrict__ hb, const ushort* __restrict__ WT,
    ushort* __restrict__ projb, const int* __restrict__ dst, int* __restrict__ cnt) {
    const int wv = threadIdx.x >> 6;
    const int lane = threadIdx.x & 63;
    const int quad = lane >> 4, l15 = lane & 15;
    const int row0 = blockIdx.x * 64;
    const int col0 = blockIdx.y * 256 + wv * 64;

    if (blockIdx.y == 0) {                       // fused dst-histogram
        int tid = blockIdx.x * 256 + threadIdx.x;
        int stride = gridDim.x * 256;
        for (int i = tid; i < EE; i += stride)
            atomicAdd(&cnt[dst[i]], 1);
    }

    short8 Af[4][2];
#pragma unroll
    for (int g = 0; g < 4; ++g) {
        const short8* ar = (const short8*)(hb + (size_t)(row0 + 16 * g + l15) * 64);
        Af[g][0] = ar[quad];
        Af[g][1] = ar[4 + quad];
    }
    short8 Bf[2][4];
#pragma unroll
    for (int t = 0; t < 4; ++t) {
        const short8* br = (const short8*)(WT + (size_t)(col0 + 16 * t + l15) * 64);
        Bf[0][t] = br[quad];
        Bf[1][t] = br[4 + quad];
    }
    f32x4 acc[4][4];
#pragma unroll
    for (int g = 0; g < 4; ++g)
#pragma unroll
        for (int t = 0; t < 4; ++t) acc[g][t] = (f32x4){0.f, 0.f, 0.f, 0.f};
#pragma unroll
    for (int g = 0; g < 4; ++g)
#pragma unroll
        for (int t = 0; t < 4; ++t) {
            acc[g][t] = __builtin_amdgcn_mfma_f32_16x16x32_bf16(Af[g][0], Bf[0][t], acc[g][t], 0, 0, 0);
            acc[g][t] = __builtin_amdgcn_mfma_f32_16x16x32_bf16(Af[g][1], Bf[1][t], acc[g][t], 0, 0, 0);
        }
#pragma unroll
    for (int g = 0; g < 4; ++g) {
        int rbase = row0 + 16 * g + quad * 4;
#pragma unroll
        for (int t = 0; t < 4; ++t) {
            size_t cb = (size_t)(col0 + 16 * t + l15);
#pragma unroll
            for (int r = 0; r < 4; ++r)
                projb[(size_t)(rbase + r) * PCOLS + cb] = f2bf(acc[g][t][r]);
        }
    }
}

// Exclusive scan of 100k dst-counts: 1 block, 1024 threads, serial chunks + LDS scan.
#define SCAN_T 1024
#define SCAN_C 98   // ceil(NN/SCAN_T)
__global__ __launch_bounds__(1024) void scan_dst_kernel(
    const int* __restrict__ cnt, int* __restrict__ off, int* __restrict__ cur) {
    __shared__ int lds[SCAN_T];
    int t = threadIdx.x;
    int lo = t * SCAN_C, hi = lo + SCAN_C;
    if (lo > NN) lo = NN;
    if (hi > NN) hi = NN;
    int s = 0;
    for (int i = lo; i < hi; ++i) s += cnt[i];
    lds[t] = s;
    __syncthreads();
    for (int o = 1; o < SCAN_T; o <<= 1) {
        int v = (t >= o) ? lds[t - o] : 0;
        __syncthreads();
        lds[t] += v;
        __syncthreads();
    }
    int base = (t > 0) ? lds[t - 1] : 0;
    for (int i = lo; i < hi; ++i) { off[i] = base; cur[i] = base; base += cnt[i]; }
    if (t == SCAN_T - 1) off[NN] = lds[SCAN_T - 1];
}

// Bucket edges by dst; payload is the proj row index pidx = src*16+rel.
__global__ void scatter_dst_kernel(const int* __restrict__ src, const int* __restrict__ dst,
                                   const int* __restrict__ rel, int* __restrict__ cur,
                                   int* __restrict__ pidx) {
    int i = blockIdx.x * blockDim.x + threadIdx.x;
    if (i < EE) {
        int pos = atomicAdd(&cur[dst[i]], 1);
        pidx[pos] = src[i] * 16 + rel[i];
    }
}

// Atomic-free aggregation: one wave per dst node, lane = output col.
// h2[v][lane] = sum over the dst-run of bf16 proj rows; single coalesced store.
__global__ __launch_bounds__(256) void aggregate_kernel(
    const int* __restrict__ off, const int* __restrict__ pidx,
    const ushort* __restrict__ projb, float* __restrict__ h2) {
    int wv = (blockIdx.x * 256 + threadIdx.x) >> 6;
    int lane = threadIdx.x & 63;
    int v = __builtin_amdgcn_readfirstlane(wv);
    if (v >= NN) return;
    int s = off[v], e = off[v + 1];
    float acc = 0.f;
    int i = s;
    for (; i + 4 <= e; i += 4) {
        int p0 = pidx[i], p1 = pidx[i + 1], p2 = pidx[i + 2], p3 = pidx[i + 3];
        float a = bf2f(projb[(size_t)p0 * 64 + lane]);
        float b = bf2f(projb[(size_t)p1 * 64 + lane]);
        float c = bf2f(projb[(size_t)p2 * 64 + lane]);
        float d = bf2f(projb[(size_t)p3 * 64 + lane]);
        acc += (a + b) + (c + d);
    }
    for (; i < e; ++i)
        acc += bf2f(projb[(size_t)pidx[i] * 64 + lane]);
    h2[(size_t)v * 64 + lane] = acc;
}

// ================= FALLBACK PATH (round-3, proven; used if ws too small) =====

__global__ void hist16_kernel(const int* __restrict__ rel, int* __restrict__ counts) {
    __shared__ int lc[NREL];
    if (threadIdx.x < NREL) lc[threadIdx.x] = 0;
    __syncthreads();
    int stride = gridDim.x * blockDim.x;
    for (int i = blockIdx.x * blockDim.x + threadIdx.x; i < EE; i += stride)
        atomicAdd(&lc[rel[i]], 1);
    __syncthreads();
    if (threadIdx.x < NREL && lc[threadIdx.x] > 0)
        atomicAdd(&counts[threadIdx.x], lc[threadIdx.x]);
}

__global__ void scan16_kernel(const int* __restrict__ counts,
                              int* __restrict__ offsets, int* __restrict__ cursors) {
    if (threadIdx.x == 0 && blockIdx.x == 0) {
        int acc = 0;
        for (int r = 0; r < NREL; ++r) { offsets[r] = acc; cursors[r] = acc; acc += counts[r]; }
        offsets[NREL] = acc;
    }
}

__global__ void scatter16_kernel(const int* __restrict__ rel, const int* __restrict__ src,
                                 const int* __restrict__ dst, int* __restrict__ cursors,
                                 int* __restrict__ src_bin, int* __restrict__ dst_bin) {
    __shared__ int lhist[NREL];
    __shared__ int lbase[NREL];
    int i = blockIdx.x * blockDim.x + threadIdx.x;
    if (threadIdx.x < NREL) lhist[threadIdx.x] = 0;
    __syncthreads();
    int r = 0, rank = 0;
    if (i < EE) { r = rel[i]; rank = atomicAdd(&lhist[r], 1); }
    __syncthreads();
    if (threadIdx.x < NREL && lhist[threadIdx.x] > 0)
        lbase[threadIdx.x] = atomicAdd(&cursors[threadIdx.x], lhist[threadIdx.x]);
    __syncthreads();
    if (i < EE) {
        int pos = lbase[r] + rank;
        src_bin[pos] = src[i];
        dst_bin[pos] = dst[i];
    }
}

__global__ __launch_bounds__(256) void edge_mfma_kernel(
    const int* __restrict__ offsets, const int* __restrict__ src_bin,
    const int* __restrict__ dst_bin, const ushort* __restrict__ hb,
    const ushort* __restrict__ WT, float* __restrict__ h2) {
    const int rel = blockIdx.y;
    const int lane = threadIdx.x & 63;
    const int quad = lane >> 4;
    const int l15 = lane & 15;
    const int start = offsets[rel];
    const int end = offsets[rel + 1];
    const int cnt = end - start;
    if (cnt <= 0) return;

    const short8* wt = (const short8*)(WT + rel * 4096);
    short8 Bf[2][4];
#pragma unroll
    for (int t = 0; t < 4; ++t) {
#pragma unroll
        for (int s = 0; s < 2; ++s)
            Bf[s][t] = wt[((t * 16 + l15) << 3) + (s << 2) + quad];
    }
    const int nw = EGX * 4;
    const int wave = blockIdx.x * 4 + (threadIdx.x >> 6);
    const int nb = (cnt + 15) >> 4;
    const int per = (nb + nw - 1) / nw;
    int b0 = wave * per;
    int b1 = b0 + per; if (b1 > nb) b1 = nb;
    const int quad4 = quad * 4;

    for (int b = b0; b < b1; ++b) {
        const int base = start + (b << 4);
        int ei = base + l15; if (ei >= end) ei = end - 1;
        int s0 = src_bin[ei];
        const short8* ar = (const short8*)(hb + (size_t)s0 * FDIM);
        short8 A0 = ar[quad];
        short8 A1 = ar[4 + quad];
        f32x4 acc[4];
#pragma unroll
        for (int t = 0; t < 4; ++t) acc[t] = (f32x4){0.f, 0.f, 0.f, 0.f};
#pragma unroll
        for (int t = 0; t < 4; ++t) {
            acc[t] = __builtin_amdgcn_mfma_f32_16x16x32_bf16(A0, Bf[0][t], acc[t], 0, 0, 0);
            acc[t] = __builtin_amdgcn_mfma_f32_16x16x32_bf16(A1, Bf[1][t], acc[t], 0, 0, 0);
        }
#pragma unroll
        for (int r = 0; r < 4; ++r) {
            int em = base + quad4 + r;
            if (em < end) {
                int dv = dst_bin[em];
                float* p = h2 + (size_t)dv * FDIM + l15;
                unsafeAtomicAdd(p,      acc[0][r]);
                unsafeAtomicAdd(p + 16, acc[1][r]);
                unsafeAtomicAdd(p + 32, acc[2][r]);
                unsafeAtomicAdd(p + 48, acc[3][r]);
            }
        }
    }
}

extern "C" void kernel_launch(void* const* d_in, const int* in_sizes, int n_in,
                              void* d_out, int out_size, void* d_ws, size_t ws_size,
                              hipStream_t stream) {
    const float* h      = (const float*)d_in[0];
    const float* weight = (const float*)d_in[1];
    const float* w_comp = (const float*)d_in[2];
    const int*   src    = (const int*)d_in[3];
    const int*   dst    = (const int*)d_in[4];
    const int*   rel    = (const int*)d_in[5];

    float* out_hnew = (float*)d_out;
    float* out_h2   = out_hnew + HN;

    char* ws = (char*)d_ws;

    // Main-path layout (all offsets 16B-aligned)
    size_t o_cnt  = 131072;                       // WT @ 0 (128 KB)
    size_t o_off  = o_cnt + 400000;               // cnt: 100000 ints
    size_t o_cur  = o_off + 400016;               // off: 100001 ints (+pad)
    size_t o_pidx = o_cur + 400000;               // cur: 100000 ints
    size_t o_hb   = o_pidx + 4000000;             // pidx: 1M ints
    size_t o_proj = o_hb + (size_t)NPAD * 128;    // hb: NPAD x 64 bf16
    size_t need   = o_proj + (size_t)NPAD * 2048; // projb: NPAD x 1024 bf16 (~205 MB)

    if (ws_size >= need) {
        ushort* WT    = (ushort*)ws;
        int*    cnt   = (int*)(ws + o_cnt);
        int*    off   = (int*)(ws + o_off);
        int*    cur   = (int*)(ws + o_cur);
        int*    pidx  = (int*)(ws + o_pidx);
        ushort* hb    = (ushort*)(ws + o_hb);
        ushort* projb = (ushort*)(ws + o_proj);

        hipLaunchKernelGGL(prep_kernel, dim3((H4 + 255) / 256), dim3(256), 0, stream,
                           (const float4*)h, (float4*)out_hnew, (ushort2*)hb,
                           weight, w_comp, WT, cnt, NN, (float4*)out_h2, 0);
        hipLaunchKernelGGL(proj_gemm_kernel, dim3(NPAD / 64, 4), dim3(256), 0, stream,
                           hb, WT, projb, dst, cnt);
        hipLaunchKernelGGL(scan_dst_kernel, dim3(1), dim3(SCAN_T), 0, stream,
                           cnt, off, cur);
        hipLaunchKernelGGL(scatter_dst_kernel, dim3((EE + 255) / 256), dim3(256), 0, stream,
                           src, dst, rel, cur, pidx);
        hipLaunchKernelGGL(aggregate_kernel, dim3(NN / 4), dim3(256), 0, stream,
                           off, pidx, projb, out_h2);
    } else {
        // Fallback: round-3 proven path (rel-sorted edge MFMA + fp32 atomics)
        ushort* WT      = (ushort*)ws;
        int*    meta    = (int*)(ws + 0x20000);
        int*    counts  = meta;
        int*    offsets = meta + 16;
        int*    cursors = meta + 33;
        int*    src_bin = (int*)(ws + 0x20400);
        int*    dst_bin = (int*)(ws + 0x20400 + 4 * EE);
        ushort* hb      = (ushort*)(ws + 0x20400 + 8 * EE);

        hipLaunchKernelGGL(prep_kernel, dim3((H4 + 255) / 256), dim3(256), 0, stream,
                           (const float4*)h, (float4*)out_hnew, (ushort2*)hb,
                           weight, w_comp, WT, counts, 16, (float4*)out_h2, 1);
        hipLaunchKernelGGL(hist16_kernel, dim3(1024), dim3(256), 0, stream, rel, counts);
        hipLaunchKernelGGL(scan16_kernel, dim3(1), dim3(64), 0, stream,
                           counts, offsets, cursors);
        hipLaunchKernelGGL(scatter16_kernel, dim3((EE + 255) / 256), dim3(256), 0, stream,
                           rel, src, dst, cursors, src_bin, dst_bin);
        hipLaunchKernelGGL(edge_mfma_kernel, dim3(EGX, NREL), dim3(256), 0, stream,
                           offsets, src_bin, dst_bin, hb, WT, out_h2);
    }
}

// Round 5
// 324.326 us; speedup vs baseline: 1.7169x; 1.7169x over previous
//
#include <hip/hip_runtime.h>
#include <hip/hip_bf16.h>

// Problem constants (match reference)
#define NN 100000
#define EE 1000000
#define FDIM 64
#define NREL 16
#define NBASE 8
#define HN (NN * FDIM)
#define H4 (HN / 4)
#define WSZ (NREL * FDIM * FDIM)   // 65536 elements
#define NPAD 100032                // NN padded to multiple of 64
#define PCOLS 1024                 // R*OUT
#define NB_SCAN ((NN + 255) / 256) // 391 scan blocks
#define EGX 128                    // fallback: blocks per rel in edge kernel

typedef __attribute__((ext_vector_type(8))) short short8;
typedef __attribute__((ext_vector_type(4))) float f32x4;

static __device__ __forceinline__ ushort f2bf(float f) {
    __hip_bfloat16 b = __float2bfloat16(f);
    return *(ushort*)&b;
}
static __device__ __forceinline__ float bf2f(ushort u) {
    unsigned x = ((unsigned)u) << 16;
    float f;
    __builtin_memcpy(&f, &x, 4);
    return f;
}

// ---------------- shared prep kernel (both paths) ----------------
// gid < czn : zero histogram counters; gid < WSZ : WT (reinterpret-view-faithful,
// stored [c=r*64+o][d] = GEMM B layout); gid < H4 : relu out + bf16 h copy.
__global__ void prep_kernel(const float4* __restrict__ h4, float4* __restrict__ out4,
                            ushort2* __restrict__ hb2,
                            const float* __restrict__ weight,
                            const float* __restrict__ w_comp, ushort* __restrict__ WT,
                            int* __restrict__ cnt, int czn,
                            float4* __restrict__ h2z, int zero_h2) {
    int gid = blockIdx.x * blockDim.x + threadIdx.x;
    if (gid < czn) cnt[gid] = 0;
    if (gid < WSZ) {
        int r = gid >> 12;
        int o = (gid >> 6) & 63;
        int d = gid & 63;
        const float* wc = w_comp + (d & 15) * NBASE;
        const float* wv = weight + (size_t)(4 * r + (d >> 4)) * 512 + o;
        float acc = 0.f;
#pragma unroll
        for (int b = 0; b < NBASE; ++b)
            acc = fmaf(wc[b], wv[b * 64], acc);
        WT[gid] = f2bf(acc);
    }
    if (gid < H4) {
        float4 v = h4[gid];
        ushort2 lo, hi;
        lo.x = f2bf(v.x); lo.y = f2bf(v.y);
        hi.x = f2bf(v.z); hi.y = f2bf(v.w);
        hb2[2 * gid] = lo;
        hb2[2 * gid + 1] = hi;
        v.x = fmaxf(v.x, 0.f); v.y = fmaxf(v.y, 0.f);
        v.z = fmaxf(v.z, 0.f); v.w = fmaxf(v.w, 0.f);
        out4[gid] = v;
        if (zero_h2) h2z[gid] = make_float4(0.f, 0.f, 0.f, 0.f);
    }
}

// ================= MAIN PATH (proj + dst-sort, atomic-free) =================

// Dense GEMM: projb[n][c] = sum_d hb[n][d] * WT[c][d]. Wave tile 64x64;
// block = 64 rows x 256 cols. Layouts HW-verified (round 3).
// blockIdx.y==0 blocks also accumulate the dst histogram (fused).
__global__ __launch_bounds__(256) void proj_gemm_kernel(
    const ushort* __restrict__ hb, const ushort* __restrict__ WT,
    ushort* __restrict__ projb, const int* __restrict__ dst, int* __restrict__ cnt) {
    const int wv = threadIdx.x >> 6;
    const int lane = threadIdx.x & 63;
    const int quad = lane >> 4, l15 = lane & 15;
    const int row0 = blockIdx.x * 64;
    const int col0 = blockIdx.y * 256 + wv * 64;

    if (blockIdx.y == 0) {                       // fused dst-histogram
        int tid = blockIdx.x * 256 + threadIdx.x;
        int stride = gridDim.x * 256;
        for (int i = tid; i < EE; i += stride)
            atomicAdd(&cnt[dst[i]], 1);
    }

    short8 Af[4][2];
#pragma unroll
    for (int g = 0; g < 4; ++g) {
        const short8* ar = (const short8*)(hb + (size_t)(row0 + 16 * g + l15) * 64);
        Af[g][0] = ar[quad];
        Af[g][1] = ar[4 + quad];
    }
    short8 Bf[2][4];
#pragma unroll
    for (int t = 0; t < 4; ++t) {
        const short8* br = (const short8*)(WT + (size_t)(col0 + 16 * t + l15) * 64);
        Bf[0][t] = br[quad];
        Bf[1][t] = br[4 + quad];
    }
    f32x4 acc[4][4];
#pragma unroll
    for (int g = 0; g < 4; ++g)
#pragma unroll
        for (int t = 0; t < 4; ++t) acc[g][t] = (f32x4){0.f, 0.f, 0.f, 0.f};
#pragma unroll
    for (int g = 0; g < 4; ++g)
#pragma unroll
        for (int t = 0; t < 4; ++t) {
            acc[g][t] = __builtin_amdgcn_mfma_f32_16x16x32_bf16(Af[g][0], Bf[0][t], acc[g][t], 0, 0, 0);
            acc[g][t] = __builtin_amdgcn_mfma_f32_16x16x32_bf16(Af[g][1], Bf[1][t], acc[g][t], 0, 0, 0);
        }
#pragma unroll
    for (int g = 0; g < 4; ++g) {
        int rbase = row0 + 16 * g + quad * 4;
#pragma unroll
        for (int t = 0; t < 4; ++t) {
            size_t cb = (size_t)(col0 + 16 * t + l15);
#pragma unroll
            for (int r = 0; r < 4; ++r)
                projb[(size_t)(rbase + r) * PCOLS + cb] = f2bf(acc[g][t][r]);
        }
    }
}

// ---- multi-block exclusive scan of the 100k dst-histogram (3 tiny stages) ----
// Stage A: per-256-block sums (coalesced load + wave reduce).
__global__ __launch_bounds__(256) void scan_a_kernel(const int* __restrict__ cnt,
                                                     int* __restrict__ bsum) {
    int i = blockIdx.x * 256 + threadIdx.x;
    int v = (i < NN) ? cnt[i] : 0;
#pragma unroll
    for (int o = 32; o > 0; o >>= 1) v += __shfl_down(v, o, 64);
    __shared__ int ws4[4];
    if ((threadIdx.x & 63) == 0) ws4[threadIdx.x >> 6] = v;
    __syncthreads();
    if (threadIdx.x == 0) bsum[blockIdx.x] = ws4[0] + ws4[1] + ws4[2] + ws4[3];
}

// Stage B: 1 block scans the 391 block sums (inclusive -> exclusive bases).
__global__ __launch_bounds__(512) void scan_b_kernel(const int* __restrict__ bsum,
                                                     int* __restrict__ bbase,
                                                     int* __restrict__ off) {
    __shared__ int lds[512];
    int t = threadIdx.x;
    int v = (t < NB_SCAN) ? bsum[t] : 0;
    lds[t] = v;
    __syncthreads();
    for (int o = 1; o < 512; o <<= 1) {
        int u = (t >= o) ? lds[t - o] : 0;
        __syncthreads();
        lds[t] += u;
        __syncthreads();
    }
    if (t < NB_SCAN) bbase[t] = lds[t] - v;
    if (t == NB_SCAN - 1) off[NN] = lds[t];
}

// Stage C: block-local exclusive scan + base; writes off and cur.
__global__ __launch_bounds__(256) void scan_c_kernel(const int* __restrict__ cnt,
                                                     const int* __restrict__ bbase,
                                                     int* __restrict__ off,
                                                     int* __restrict__ cur) {
    __shared__ int lds[256];
    int i = blockIdx.x * 256 + threadIdx.x;
    int t = threadIdx.x;
    int v = (i < NN) ? cnt[i] : 0;
    lds[t] = v;
    __syncthreads();
    for (int o = 1; o < 256; o <<= 1) {
        int u = (t >= o) ? lds[t - o] : 0;
        __syncthreads();
        lds[t] += u;
        __syncthreads();
    }
    if (i < NN) {
        int excl = lds[t] - v + bbase[blockIdx.x];
        off[i] = excl;
        cur[i] = excl;
    }
}

// Bucket edges by dst; payload pidx = src*16+rel.
__global__ void scatter_dst_kernel(const int* __restrict__ src, const int* __restrict__ dst,
                                   const int* __restrict__ rel, int* __restrict__ cur,
                                   int* __restrict__ pidx) {
    int i = blockIdx.x * blockDim.x + threadIdx.x;
    if (i < EE) {
        int pos = atomicAdd(&cur[dst[i]], 1);
        pidx[pos] = src[i] * 16 + rel[i];
    }
}

// Atomic-free aggregation: one wave per dst node, lane = output col.
__global__ __launch_bounds__(256) void aggregate_kernel(
    const int* __restrict__ off, const int* __restrict__ pidx,
    const ushort* __restrict__ projb, float* __restrict__ h2) {
    int wv = (blockIdx.x * 256 + threadIdx.x) >> 6;
    int lane = threadIdx.x & 63;
    int v = __builtin_amdgcn_readfirstlane(wv);
    if (v >= NN) return;
    int s = off[v], e = off[v + 1];
    float acc = 0.f;
    int i = s;
    for (; i + 4 <= e; i += 4) {
        int p0 = pidx[i], p1 = pidx[i + 1], p2 = pidx[i + 2], p3 = pidx[i + 3];
        float a = bf2f(projb[(size_t)p0 * 64 + lane]);
        float b = bf2f(projb[(size_t)p1 * 64 + lane]);
        float c = bf2f(projb[(size_t)p2 * 64 + lane]);
        float d = bf2f(projb[(size_t)p3 * 64 + lane]);
        acc += (a + b) + (c + d);
    }
    for (; i < e; ++i)
        acc += bf2f(projb[(size_t)pidx[i] * 64 + lane]);
    h2[(size_t)v * 64 + lane] = acc;
}

// ================= FALLBACK PATH (round-3, proven; used if ws too small) =====

__global__ void hist16_kernel(const int* __restrict__ rel, int* __restrict__ counts) {
    __shared__ int lc[NREL];
    if (threadIdx.x < NREL) lc[threadIdx.x] = 0;
    __syncthreads();
    int stride = gridDim.x * blockDim.x;
    for (int i = blockIdx.x * blockDim.x + threadIdx.x; i < EE; i += stride)
        atomicAdd(&lc[rel[i]], 1);
    __syncthreads();
    if (threadIdx.x < NREL && lc[threadIdx.x] > 0)
        atomicAdd(&counts[threadIdx.x], lc[threadIdx.x]);
}

__global__ void scan16_kernel(const int* __restrict__ counts,
                              int* __restrict__ offsets, int* __restrict__ cursors) {
    if (threadIdx.x == 0 && blockIdx.x == 0) {
        int acc = 0;
        for (int r = 0; r < NREL; ++r) { offsets[r] = acc; cursors[r] = acc; acc += counts[r]; }
        offsets[NREL] = acc;
    }
}

__global__ void scatter16_kernel(const int* __restrict__ rel, const int* __restrict__ src,
                                 const int* __restrict__ dst, int* __restrict__ cursors,
                                 int* __restrict__ src_bin, int* __restrict__ dst_bin) {
    __shared__ int lhist[NREL];
    __shared__ int lbase[NREL];
    int i = blockIdx.x * blockDim.x + threadIdx.x;
    if (threadIdx.x < NREL) lhist[threadIdx.x] = 0;
    __syncthreads();
    int r = 0, rank = 0;
    if (i < EE) { r = rel[i]; rank = atomicAdd(&lhist[r], 1); }
    __syncthreads();
    if (threadIdx.x < NREL && lhist[threadIdx.x] > 0)
        lbase[threadIdx.x] = atomicAdd(&cursors[threadIdx.x], lhist[threadIdx.x]);
    __syncthreads();
    if (i < EE) {
        int pos = lbase[r] + rank;
        src_bin[pos] = src[i];
        dst_bin[pos] = dst[i];
    }
}

__global__ __launch_bounds__(256) void edge_mfma_kernel(
    const int* __restrict__ offsets, const int* __restrict__ src_bin,
    const int* __restrict__ dst_bin, const ushort* __restrict__ hb,
    const ushort* __restrict__ WT, float* __restrict__ h2) {
    const int rel = blockIdx.y;
    const int lane = threadIdx.x & 63;
    const int quad = lane >> 4;
    const int l15 = lane & 15;
    const int start = offsets[rel];
    const int end = offsets[rel + 1];
    const int cnt = end - start;
    if (cnt <= 0) return;

    const short8* wt = (const short8*)(WT + rel * 4096);
    short8 Bf[2][4];
#pragma unroll
    for (int t = 0; t < 4; ++t) {
#pragma unroll
        for (int s = 0; s < 2; ++s)
            Bf[s][t] = wt[((t * 16 + l15) << 3) + (s << 2) + quad];
    }
    const int nw = EGX * 4;
    const int wave = blockIdx.x * 4 + (threadIdx.x >> 6);
    const int nb = (cnt + 15) >> 4;
    const int per = (nb + nw - 1) / nw;
    int b0 = wave * per;
    int b1 = b0 + per; if (b1 > nb) b1 = nb;
    const int quad4 = quad * 4;

    for (int b = b0; b < b1; ++b) {
        const int base = start + (b << 4);
        int ei = base + l15; if (ei >= end) ei = end - 1;
        int s0 = src_bin[ei];
        const short8* ar = (const short8*)(hb + (size_t)s0 * FDIM);
        short8 A0 = ar[quad];
        short8 A1 = ar[4 + quad];
        f32x4 acc[4];
#pragma unroll
        for (int t = 0; t < 4; ++t) acc[t] = (f32x4){0.f, 0.f, 0.f, 0.f};
#pragma unroll
        for (int t = 0; t < 4; ++t) {
            acc[t] = __builtin_amdgcn_mfma_f32_16x16x32_bf16(A0, Bf[0][t], acc[t], 0, 0, 0);
            acc[t] = __builtin_amdgcn_mfma_f32_16x16x32_bf16(A1, Bf[1][t], acc[t], 0, 0, 0);
        }
#pragma unroll
        for (int r = 0; r < 4; ++r) {
            int em = base + quad4 + r;
            if (em < end) {
                int dv = dst_bin[em];
                float* p = h2 + (size_t)dv * FDIM + l15;
                unsafeAtomicAdd(p,      acc[0][r]);
                unsafeAtomicAdd(p + 16, acc[1][r]);
                unsafeAtomicAdd(p + 32, acc[2][r]);
                unsafeAtomicAdd(p + 48, acc[3][r]);
            }
        }
    }
}

extern "C" void kernel_launch(void* const* d_in, const int* in_sizes, int n_in,
                              void* d_out, int out_size, void* d_ws, size_t ws_size,
                              hipStream_t stream) {
    const float* h      = (const float*)d_in[0];
    const float* weight = (const float*)d_in[1];
    const float* w_comp = (const float*)d_in[2];
    const int*   src    = (const int*)d_in[3];
    const int*   dst    = (const int*)d_in[4];
    const int*   rel    = (const int*)d_in[5];

    float* out_hnew = (float*)d_out;
    float* out_h2   = out_hnew + HN;

    char* ws = (char*)d_ws;

    // Main-path layout (all offsets 16B-aligned)
    size_t o_cnt  = 131072;                       // WT @ 0 (128 KB)
    size_t o_off  = o_cnt + 400000;               // cnt: 100000 ints
    size_t o_cur  = o_off + 400016;               // off: 100001 ints (+pad)
    size_t o_pidx = o_cur + 400000;               // cur: 100000 ints
    size_t o_bsum = o_pidx + 4000000;             // pidx: 1M ints
    size_t o_bbas = o_bsum + 4 * ((NB_SCAN + 3) & ~3);
    size_t o_hb   = o_bbas + 4 * ((NB_SCAN + 3) & ~3);
    size_t o_proj = o_hb + (size_t)NPAD * 128;    // hb: NPAD x 64 bf16
    size_t need   = o_proj + (size_t)NPAD * 2048; // projb: NPAD x 1024 bf16 (~205 MB)

    if (ws_size >= need) {
        ushort* WT    = (ushort*)ws;
        int*    cnt   = (int*)(ws + o_cnt);
        int*    off   = (int*)(ws + o_off);
        int*    cur   = (int*)(ws + o_cur);
        int*    pidx  = (int*)(ws + o_pidx);
        int*    bsum  = (int*)(ws + o_bsum);
        int*    bbase = (int*)(ws + o_bbas);
        ushort* hb    = (ushort*)(ws + o_hb);
        ushort* projb = (ushort*)(ws + o_proj);

        hipLaunchKernelGGL(prep_kernel, dim3((H4 + 255) / 256), dim3(256), 0, stream,
                           (const float4*)h, (float4*)out_hnew, (ushort2*)hb,
                           weight, w_comp, WT, cnt, NN, (float4*)out_h2, 0);
        hipLaunchKernelGGL(proj_gemm_kernel, dim3(NPAD / 64, 4), dim3(256), 0, stream,
                           hb, WT, projb, dst, cnt);
        hipLaunchKernelGGL(scan_a_kernel, dim3(NB_SCAN), dim3(256), 0, stream, cnt, bsum);
        hipLaunchKernelGGL(scan_b_kernel, dim3(1), dim3(512), 0, stream, bsum, bbase, off);
        hipLaunchKernelGGL(scan_c_kernel, dim3(NB_SCAN), dim3(256), 0, stream,
                           cnt, bbase, off, cur);
        hipLaunchKernelGGL(scatter_dst_kernel, dim3((EE + 255) / 256), dim3(256), 0, stream,
                           src, dst, rel, cur, pidx);
        hipLaunchKernelGGL(aggregate_kernel, dim3(NN / 4), dim3(256), 0, stream,
                           off, pidx, projb, out_h2);
    } else {
        // Fallback: round-3 proven path (rel-sorted edge MFMA + fp32 atomics)
        ushort* WT      = (ushort*)ws;
        int*    meta    = (int*)(ws + 0x20000);
        int*    counts  = meta;
        int*    offsets = meta + 16;
        int*    cursors = meta + 33;
        int*    src_bin = (int*)(ws + 0x20400);
        int*    dst_bin = (int*)(ws + 0x20400 + 4 * EE);
        ushort* hb      = (ushort*)(ws + 0x20400 + 8 * EE);

        hipLaunchKernelGGL(prep_kernel, dim3((H4 + 255) / 256), dim3(256), 0, stream,
                           (const float4*)h, (float4*)out_hnew, (ushort2*)hb,
                           weight, w_comp, WT, counts, 16, (float4*)out_h2, 1);
        hipLaunchKernelGGL(hist16_kernel, dim3(1024), dim3(256), 0, stream, rel, counts);
        hipLaunchKernelGGL(scan16_kernel, dim3(1), dim3(64), 0, stream,
                           counts, offsets, cursors);
        hipLaunchKernelGGL(scatter16_kernel, dim3((EE + 255) / 256), dim3(256), 0, stream,
                           rel, src, dst, cursors, src_bin, dst_bin);
        hipLaunchKernelGGL(edge_mfma_kernel, dim3(EGX, NREL), dim3(256), 0, stream,
                           offsets, src_bin, dst_bin, hb, WT, out_h2);
    }
}